// Round 2
// baseline (195.092 us; speedup 1.0000x reference)
//
#include <hip/hip_runtime.h>
#include <hip/hip_fp16.h>
#include <math.h>
#include <stdint.h>

#define N_STEPS 256
#define DENSITY_SCALE 10.0f
#define REF_EPS 1e-8f

typedef uint32_t u32_a2 __attribute__((aligned(2)));
typedef uint2 uint2_a4 __attribute__((aligned(4)));

__device__ __forceinline__ float clip01(float v) {
    return fminf(fmaxf(v, 0.0f), 1.0f);
}

__device__ __forceinline__ float safe_inv(float d) {
    float denom = d;
    if (fabsf(d) < REF_EPS) {
        float s = (d > 0.0f) ? 1.0f : ((d < 0.0f) ? -1.0f : 0.0f);
        denom = s * REF_EPS + REF_EPS;   // may be 0 -> inf, matches jnp
    }
    return 1.0f / denom;
}

__device__ __forceinline__ uint32_t q255(float v) {
    return (uint32_t)__float2int_rn(clip01(v) * 255.0f);
}

// ---------------- pass A: fp32 grid -> u8 grid (read-once, coalesced) -------
// 16 voxels per thread. Also zeroes the compaction counter.
__global__ __launch_bounds__(256) void quantize_kernel(
    const float* __restrict__ g, uint8_t* __restrict__ q8, int* __restrict__ counter)
{
    if (blockIdx.x == 0 && threadIdx.x == 0) *counter = 0;
    int t = blockIdx.x * blockDim.x + threadIdx.x;   // [0, n_grid/16)
    const float4* src = (const float4*)g + (size_t)t * 4;
    float4 v0 = src[0], v1 = src[1], v2 = src[2], v3 = src[3];
    uint4 o;
    o.x = q255(v0.x) | (q255(v0.y) << 8) | (q255(v0.z) << 16) | (q255(v0.w) << 24);
    o.y = q255(v1.x) | (q255(v1.y) << 8) | (q255(v1.z) << 16) | (q255(v1.w) << 24);
    o.z = q255(v2.x) | (q255(v2.y) << 8) | (q255(v2.z) << 16) | (q255(v2.w) << 24);
    o.w = q255(v3.x) | (q255(v3.y) << 8) | (q255(v3.z) << 16) | (q255(v3.w) << 24);
    *((uint4*)(q8 + (size_t)t * 16)) = o;
}

// ---------------- pass B: u8 grid -> quad table -----------------------------
// quad[z][y][x] = u8x4 {v(z,y,x), v(z,y+1,x), v(z+1,y,x), v(z+1,y+1,x)}
// 16 x-values per thread: 4 x 16B u8 reads (rows y/y+1 at z/z+1), 64B quad write.
// The 4x row re-read redundancy is now over the 16MB u8 grid -> L2-resident.
__global__ __launch_bounds__(256) void quadbuild_kernel(
    const uint8_t* __restrict__ q8, uint32_t* __restrict__ quad)
{
    int t = blockIdx.x * blockDim.x + threadIdx.x;   // [0, 256*256*16)
    int x16 = (t & 15) << 4;
    int zy = t >> 4;
    int z = zy >> 8;
    int y = zy & 255;
    int yp = (y == 255) ? y : y + 1;                 // clamped rows: unused by march
    int zp = (z == 255) ? z : z + 1;
    uint4 A = *(const uint4*)(q8 + ((z  << 16) + (y  << 8) + x16));
    uint4 B = *(const uint4*)(q8 + ((z  << 16) + (yp << 8) + x16));
    uint4 C = *(const uint4*)(q8 + ((zp << 16) + (y  << 8) + x16));
    uint4 D = *(const uint4*)(q8 + ((zp << 16) + (yp << 8) + x16));

    const uint32_t* a = (const uint32_t*)&A;
    const uint32_t* b = (const uint32_t*)&B;
    const uint32_t* c = (const uint32_t*)&C;
    const uint32_t* d = (const uint32_t*)&D;
    uint32_t* dst = quad + ((size_t)(zy << 8) + x16);

    #pragma unroll
    for (int w = 0; w < 4; ++w) {
        uint32_t aw = a[w], bw = b[w], cw = c[w], dw = d[w];
        uint4 o;
        o.x = ( aw        & 0xffu) | (( bw        & 0xffu) << 8) |
              (( cw        & 0xffu) << 16) | (( dw        & 0xffu) << 24);
        o.y = ((aw >>  8) & 0xffu) | (((bw >>  8) & 0xffu) << 8) |
              (((cw >>  8) & 0xffu) << 16) | (((dw >>  8) & 0xffu) << 24);
        o.z = ((aw >> 16) & 0xffu) | (((bw >> 16) & 0xffu) << 8) |
              (((cw >> 16) & 0xffu) << 16) | (((dw >> 16) & 0xffu) << 24);
        o.w = ((aw >> 24) & 0xffu) | (((bw >> 24) & 0xffu) << 8) |
              (((cw >> 24) & 0xffu) << 16) | (((dw >> 24) & 0xffu) << 24);
        *(uint4*)(dst + w * 4) = o;
    }
}

// ---- legacy one-pass repack (fallback when ws has no room for u8 temp) ----
__global__ __launch_bounds__(256) void repack_quad_kernel(
    const float* __restrict__ g, uint32_t* __restrict__ quad, int* __restrict__ counter)
{
    if (blockIdx.x == 0 && threadIdx.x == 0) *counter = 0;
    int t = blockIdx.x * blockDim.x + threadIdx.x;     // [0, 256*256*64)
    int x4 = (t & 63) << 2;
    int zy = t >> 6;
    int z = zy >> 8;
    int y = zy & 255;
    int yp = (y == 255) ? y : y + 1;
    int zp = (z == 255) ? z : z + 1;
    float4 a = *(const float4*)(g + ((z  << 16) + (y  << 8) + x4));
    float4 b = *(const float4*)(g + ((z  << 16) + (yp << 8) + x4));
    float4 c = *(const float4*)(g + ((zp << 16) + (y  << 8) + x4));
    float4 d = *(const float4*)(g + ((zp << 16) + (yp << 8) + x4));
    uint4 o;
    o.x = q255(a.x) | (q255(b.x) << 8) | (q255(c.x) << 16) | (q255(d.x) << 24);
    o.y = q255(a.y) | (q255(b.y) << 8) | (q255(c.y) << 16) | (q255(d.y) << 24);
    o.z = q255(a.z) | (q255(b.z) << 8) | (q255(c.z) << 16) | (q255(d.z) << 24);
    o.w = q255(a.w) | (q255(b.w) << 8) | (q255(c.w) << 16) | (q255(d.w) << 24);
    *(uint4*)(quad + ((zy << 8) + x4)) = o;
}

// ---------------- setup: slab test + wave-ballot compaction ----------------
__global__ __launch_bounds__(256) void setup_kernel(
    const float* __restrict__ rays, float* __restrict__ out,
    float* __restrict__ compactF, int* __restrict__ compactI,
    int* __restrict__ counter, int n_rays)
{
    int ray = blockIdx.x * blockDim.x + threadIdx.x;
    bool valid = false;
    float ox = 0, oy = 0, oz = 0, dx = 0, dy = 0, dz = 0, tmin = 0, seg = 0;

    if (ray < n_rays) {
        const float* r = rays + ray * 6;
        ox = r[0]; oy = r[1]; oz = r[2];
        dx = r[3]; dy = r[4]; dz = r[5];
        float nrm = sqrtf(dx*dx + dy*dy + dz*dz) + REF_EPS;
        float inv_n = 1.0f / nrm;
        dx *= inv_n; dy *= inv_n; dz *= inv_n;
        float ixv = safe_inv(dx), iyv = safe_inv(dy), izv = safe_inv(dz);
        float tax = (-1.0f - ox) * ixv, tbx = (1.0f - ox) * ixv;
        float tay = (-1.0f - oy) * iyv, tby = (1.0f - oy) * iyv;
        float taz = (-1.0f - oz) * izv, tbz = (1.0f - oz) * izv;
        tmin = fmaxf(fmaxf(fminf(tax, tbx), fminf(tay, tby)), fminf(taz, tbz));
        float tmax = fminf(fminf(fmaxf(tax, tbx), fmaxf(tay, tby)), fmaxf(taz, tbz));
        tmin = fmaxf(tmin, 0.0f);
        valid = tmax > tmin;
        seg = valid ? (tmax - tmin) : 0.0f;
    }

    unsigned long long mask = __ballot(valid);
    int lane = threadIdx.x & 63;
    int nbefore = __popcll(mask & ((1ull << lane) - 1ull));
    int total = __popcll(mask);
    int base = 0;
    if (lane == 0) base = atomicAdd(counter, total);
    base = __shfl(base, 0);

    if (valid) {
        int idx = base + nbefore;
        float4* dst = (float4*)(compactF + (size_t)idx * 8);
        dst[0] = make_float4(ox, oy, oz, dx);
        dst[1] = make_float4(dy, dz, tmin, seg);
        compactI[idx] = ray;
    } else if (ray < n_rays) {
        out[ray] = 1.0f;
    }
}

// -------- march: 16 threads/ray, grid-stride over compact rays, u8 quad grid --------
__global__ __launch_bounds__(256, 8) void march_kernel(
    const float* __restrict__ compactF, const int* __restrict__ compactI,
    const int* __restrict__ counter, const uint32_t* __restrict__ quad,
    float* __restrict__ out)
{
    int gid = blockIdx.x * blockDim.x + threadIdx.x;
    int sub = gid & 15;
    int nvalid = *counter;
    int stride = (gridDim.x * blockDim.x) >> 4;

    for (int ray = gid >> 4; ray < nvalid; ray += stride) {
        const float4* c = (const float4*)(compactF + (size_t)ray * 8);
        float4 c0 = c[0], c1 = c[1];
        float ox = c0.x, oy = c0.y, oz = c0.z;
        float dx = c0.w, dy = c1.x, dz = c1.y;
        float tmin = c1.z, seg = c1.w;

        // gx(i) = (ox + (tmin + seg*(i+0.5)/256)*dx + 1) * 127.5  ==  gx0 + i*gsx
        float s   = seg * (1.0f / (float)N_STEPS);
        float t0  = fmaf(0.5f, s, tmin);
        float dxs = dx * 127.5f, dys = dy * 127.5f, dzs = dz * 127.5f;
        float gsx = dxs * s, gsy = dys * s, gsz = dzs * s;
        float gx0 = fmaf(t0, dxs, fmaf(ox, 127.5f, 127.5f));
        float gy0 = fmaf(t0, dys, fmaf(oy, 127.5f, 127.5f));
        float gz0 = fmaf(t0, dzs, fmaf(oz, 127.5f, 127.5f));

        float sum = 0.0f;
        #pragma unroll 8
        for (int i = sub; i < N_STEPS; i += 16) {
            float fi = (float)i;
            float gx = fmaf(fi, gsx, gx0);
            float gy = fmaf(fi, gsy, gy0);
            float gz = fmaf(fi, gsz, gz0);

            float fx0 = floorf(gx), fy0 = floorf(gy), fz0 = floorf(gz);
            int x0 = (int)fminf(fmaxf(fx0, 0.0f), 254.0f);
            int y0 = (int)fminf(fmaxf(fy0, 0.0f), 254.0f);
            int z0 = (int)fminf(fmaxf(fz0, 0.0f), 254.0f);
            float fx = fminf(fmaxf(gx - (float)x0, 0.0f), 1.0f);
            float fy = fminf(fmaxf(gy - (float)y0, 0.0f), 1.0f);
            float fz = fminf(fmaxf(gz - (float)z0, 0.0f), 1.0f);

            int vidx = (z0 << 16) + (y0 << 8) + x0;
            uint2 v = *(const uint2_a4*)(quad + vidx);
            // v.x bytes: c000,c010,c100,c110 ; v.y bytes: c001,c011,c101,c111
            float c000 = (float)( v.x        & 0xffu);
            float c010 = (float)((v.x >>  8) & 0xffu);
            float c100 = (float)((v.x >> 16) & 0xffu);
            float c110 = (float)( v.x >> 24        );
            float c001 = (float)( v.y        & 0xffu);
            float c011 = (float)((v.y >>  8) & 0xffu);
            float c101 = (float)((v.y >> 16) & 0xffu);
            float c111 = (float)( v.y >> 24        );

            float omfx = 1.0f - fx;
            float c00 = c000 * omfx + c001 * fx;
            float c01 = c010 * omfx + c011 * fx;
            float c10 = c100 * omfx + c101 * fx;
            float c11 = c110 * omfx + c111 * fx;
            float omfy = 1.0f - fy;
            float cc0 = c00 * omfy + c01 * fy;
            float cc1 = c10 * omfy + c11 * fy;
            sum += cc0 * (1.0f - fz) + cc1 * fz;   // scaled by 255
        }

        sum += __shfl_xor(sum, 1);
        sum += __shfl_xor(sum, 2);
        sum += __shfl_xor(sum, 4);
        sum += __shfl_xor(sum, 8);

        if (sub == 0) {
            float dt = seg * (1.0f / (float)N_STEPS);
            float tau = (DENSITY_SCALE / 255.0f) * sum * dt;
            out[compactI[ray]] = expf(-tau);
        }
    }
}

// ---------------- fallback: fp16 flat grid, 8 threads per ray (round-2) -----
__global__ __launch_bounds__(256) void repack_kernel(
    const float* __restrict__ g, __half* __restrict__ gh, int n)
{
    int i = (blockIdx.x * blockDim.x + threadIdx.x) * 4;
    if (i >= n) return;
    float4 v = *(const float4*)(g + i);
    __half2* dst = (__half2*)(gh + i);
    dst[0] = __floats2half2_rn(clip01(v.x), clip01(v.y));
    dst[1] = __floats2half2_rn(clip01(v.z), clip01(v.w));
}

__global__ __launch_bounds__(256) void transmittance_h_kernel(
    const float* __restrict__ rays, const __half* __restrict__ gh,
    float* __restrict__ out, int n_rays)
{
    int gid = blockIdx.x * blockDim.x + threadIdx.x;
    int ray = gid >> 3;
    int sub = gid & 7;
    if (ray >= n_rays) return;

    const float* r = rays + ray * 6;
    float ox = r[0], oy = r[1], oz = r[2];
    float dx = r[3], dy = r[4], dz = r[5];
    float nrm = sqrtf(dx*dx + dy*dy + dz*dz) + REF_EPS;
    float inv_n = 1.0f / nrm;
    dx *= inv_n; dy *= inv_n; dz *= inv_n;
    float ixv = safe_inv(dx), iyv = safe_inv(dy), izv = safe_inv(dz);
    float tax = (-1.0f - ox) * ixv, tbx = (1.0f - ox) * ixv;
    float tay = (-1.0f - oy) * iyv, tby = (1.0f - oy) * iyv;
    float taz = (-1.0f - oz) * izv, tbz = (1.0f - oz) * izv;
    float tmin = fmaxf(fmaxf(fminf(tax, tbx), fminf(tay, tby)), fminf(taz, tbz));
    float tmax = fminf(fminf(fmaxf(tax, tbx), fmaxf(tay, tby)), fmaxf(taz, tbz));
    tmin = fmaxf(tmin, 0.0f);
    bool valid = tmax > tmin;
    float seg = valid ? (tmax - tmin) : 0.0f;
    float sum = 0.0f;

    if (valid) {
        #pragma unroll 4
        for (int i = sub; i < N_STEPS; i += 8) {
            float frac = ((float)i + 0.5f) * (1.0f / (float)N_STEPS);
            float t = fmaf(seg, frac, tmin);
            float px = fmaf(t, dx, ox);
            float py = fmaf(t, dy, oy);
            float pz = fmaf(t, dz, oz);
            float gx = (px + 1.0f) * (0.5f * 255.0f);
            float gy = (py + 1.0f) * (0.5f * 255.0f);
            float gz = (pz + 1.0f) * (0.5f * 255.0f);
            float fx0 = floorf(gx), fy0 = floorf(gy), fz0 = floorf(gz);
            int x0 = (int)fminf(fmaxf(fx0, 0.0f), 254.0f);
            int y0 = (int)fminf(fmaxf(fy0, 0.0f), 254.0f);
            int z0 = (int)fminf(fmaxf(fz0, 0.0f), 254.0f);
            float fx = fminf(fmaxf(gx - (float)x0, 0.0f), 1.0f);
            float fy = fminf(fmaxf(gy - (float)y0, 0.0f), 1.0f);
            float fz = fminf(fmaxf(gz - (float)z0, 0.0f), 1.0f);
            const __half* p0 = gh + ((z0 << 16) + (y0 << 8) + x0);
            u32_a2 a00 = *(const u32_a2*)(const void*)(p0);
            u32_a2 a01 = *(const u32_a2*)(const void*)(p0 + 256);
            u32_a2 a10 = *(const u32_a2*)(const void*)(p0 + 65536);
            u32_a2 a11 = *(const u32_a2*)(const void*)(p0 + 65536 + 256);
            float2 f00 = __half22float2(*(__half2*)&a00);
            float2 f01 = __half22float2(*(__half2*)&a01);
            float2 f10 = __half22float2(*(__half2*)&a10);
            float2 f11 = __half22float2(*(__half2*)&a11);
            float omfx = 1.0f - fx;
            float c00 = f00.x * omfx + f00.y * fx;
            float c01 = f01.x * omfx + f01.y * fx;
            float c10 = f10.x * omfx + f10.y * fx;
            float c11 = f11.x * omfx + f11.y * fx;
            float omfy = 1.0f - fy;
            float cc0 = c00 * omfy + c01 * fy;
            float cc1 = c10 * omfy + c11 * fy;
            sum += cc0 * (1.0f - fz) + cc1 * fz;
        }
    }

    sum += __shfl_xor(sum, 1);
    sum += __shfl_xor(sum, 2);
    sum += __shfl_xor(sum, 4);

    if (sub == 0) {
        float result = 1.0f;
        if (valid) {
            float dt = seg * (1.0f / (float)N_STEPS);
            float tau = DENSITY_SCALE * sum * dt;
            result = expf(-tau);
        }
        out[ray] = result;
    }
}

// ---------------- fallback: fp32 grid, 4 threads per ray (round-1) ----------
__global__ __launch_bounds__(256) void transmittance_kernel(
    const float* __restrict__ rays, const float* __restrict__ grid,
    float* __restrict__ out, int n_rays)
{
    int gid = blockIdx.x * blockDim.x + threadIdx.x;
    int ray = gid >> 2;
    int sub = gid & 3;
    if (ray >= n_rays) return;
    const float* r = rays + ray * 6;
    float ox = r[0], oy = r[1], oz = r[2];
    float dx = r[3], dy = r[4], dz = r[5];
    float nrm = sqrtf(dx*dx + dy*dy + dz*dz) + REF_EPS;
    float inv_n = 1.0f / nrm;
    dx *= inv_n; dy *= inv_n; dz *= inv_n;
    float ixv = safe_inv(dx), iyv = safe_inv(dy), izv = safe_inv(dz);
    float tax = (-1.0f - ox) * ixv, tbx = (1.0f - ox) * ixv;
    float tay = (-1.0f - oy) * iyv, tby = (1.0f - oy) * iyv;
    float taz = (-1.0f - oz) * izv, tbz = (1.0f - oz) * izv;
    float tmin = fmaxf(fmaxf(fminf(tax, tbx), fminf(tay, tby)), fminf(taz, tbz));
    float tmax = fminf(fminf(fmaxf(tax, tbx), fmaxf(tay, tby)), fmaxf(taz, tbz));
    tmin = fmaxf(tmin, 0.0f);
    bool valid = tmax > tmin;
    float result = 1.0f;
    float seg = valid ? (tmax - tmin) : 0.0f;
    float sum = 0.0f;
    if (valid) {
        #pragma unroll 4
        for (int i = sub; i < N_STEPS; i += 4) {
            float frac = ((float)i + 0.5f) * (1.0f / (float)N_STEPS);
            float t = fmaf(seg, frac, tmin);
            float px = fmaf(t, dx, ox);
            float py = fmaf(t, dy, oy);
            float pz = fmaf(t, dz, oz);
            float gx = (px + 1.0f) * (0.5f * 255.0f);
            float gy = (py + 1.0f) * (0.5f * 255.0f);
            float gz = (pz + 1.0f) * (0.5f * 255.0f);
            float fx0 = floorf(gx), fy0 = floorf(gy), fz0 = floorf(gz);
            int x0 = (int)fminf(fmaxf(fx0, 0.0f), 254.0f);
            int y0 = (int)fminf(fmaxf(fy0, 0.0f), 254.0f);
            int z0 = (int)fminf(fmaxf(fz0, 0.0f), 254.0f);
            float fx = fminf(fmaxf(gx - (float)x0, 0.0f), 1.0f);
            float fy = fminf(fmaxf(gy - (float)y0, 0.0f), 1.0f);
            float fz = fminf(fmaxf(gz - (float)z0, 0.0f), 1.0f);
            const float* p0 = grid + ((z0 << 16) + (y0 << 8) + x0);
            const float* p1 = p0 + 65536;
            float c000 = p0[0],   c001 = p0[1];
            float c010 = p0[256], c011 = p0[257];
            float c100 = p1[0],   c101 = p1[1];
            float c110 = p1[256], c111 = p1[257];
            float omfx = 1.0f - fx;
            float c00 = c000 * omfx + c001 * fx;
            float c01 = c010 * omfx + c011 * fx;
            float c10 = c100 * omfx + c101 * fx;
            float c11 = c110 * omfx + c111 * fx;
            float omfy = 1.0f - fy;
            float cc0 = c00 * omfy + c01 * fy;
            float cc1 = c10 * omfy + c11 * fy;
            sum += cc0 * (1.0f - fz) + cc1 * fz;
        }
    }
    sum += __shfl_xor(sum, 1);
    sum += __shfl_xor(sum, 2);
    if (valid) {
        float dt = seg * (1.0f / (float)N_STEPS);
        float tau = DENSITY_SCALE * sum * dt;
        result = expf(-tau);
    }
    if (sub == 0) out[ray] = result;
}

extern "C" void kernel_launch(void* const* d_in, const int* in_sizes, int n_in,
                              void* d_out, int out_size, void* d_ws, size_t ws_size,
                              hipStream_t stream) {
    const float* rays = (const float*)d_in[0];   // [65536, 6] fp32
    const float* grid = (const float*)d_in[1];   // [256,256,256] fp32
    float* out = (float*)d_out;
    int n_rays = in_sizes[0] / 6;
    int n_grid = in_sizes[1];                    // 16777216

    const size_t QUAD_BYTES = (size_t)n_grid * 4;          // 64 MB u8-quad grid
    const size_t Q8_BYTES   = (size_t)n_grid;              // 16 MB u8 temp
    const size_t CF_BYTES   = (size_t)n_rays * 8 * 4;
    const size_t CI_BYTES   = (size_t)n_rays * 4;
    const size_t need_full2 = QUAD_BYTES + Q8_BYTES + CF_BYTES + CI_BYTES + 256;
    const size_t need_full  = QUAD_BYTES + CF_BYTES + CI_BYTES + 256;
    const size_t need_half  = (size_t)n_grid * 2;          // 32 MB fp16 grid

    if (ws_size >= need_full2) {
        // two-pass repack: fp32 -> u8 (read-once), then u8 -> quad (L2-resident reads)
        uint32_t* quad     = (uint32_t*)d_ws;
        uint8_t*  q8       = (uint8_t*)d_ws + QUAD_BYTES;
        float*    compactF = (float*)((char*)d_ws + QUAD_BYTES + Q8_BYTES);
        int*      compactI = (int*)((char*)d_ws + QUAD_BYTES + Q8_BYTES + CF_BYTES);
        int*      counter  = (int*)((char*)d_ws + QUAD_BYTES + Q8_BYTES + CF_BYTES + CI_BYTES);

        quantize_kernel<<<n_grid / 16 / 256, 256, 0, stream>>>(grid, q8, counter);
        quadbuild_kernel<<<n_grid / 16 / 256, 256, 0, stream>>>(q8, quad);
        setup_kernel<<<(n_rays + 255) / 256, 256, 0, stream>>>(
            rays, out, compactF, compactI, counter, n_rays);
        march_kernel<<<4096, 256, 0, stream>>>(compactF, compactI, counter, quad, out);
    } else if (ws_size >= need_full) {
        uint32_t* quad     = (uint32_t*)d_ws;
        float*    compactF = (float*)((char*)d_ws + QUAD_BYTES);
        int*      compactI = (int*)((char*)d_ws + QUAD_BYTES + CF_BYTES);
        int*      counter  = (int*)((char*)d_ws + QUAD_BYTES + CF_BYTES + CI_BYTES);

        int rp_threads = n_grid / 4;
        repack_quad_kernel<<<(rp_threads + 255) / 256, 256, 0, stream>>>(grid, quad, counter);
        setup_kernel<<<(n_rays + 255) / 256, 256, 0, stream>>>(
            rays, out, compactF, compactI, counter, n_rays);
        march_kernel<<<4096, 256, 0, stream>>>(compactF, compactI, counter, quad, out);
    } else if (ws_size >= need_half) {
        __half* gh = (__half*)d_ws;
        int rp_threads = n_grid / 4;
        repack_kernel<<<(rp_threads + 255) / 256, 256, 0, stream>>>(grid, gh, n_grid);
        int total_threads = n_rays * 8;
        transmittance_h_kernel<<<(total_threads + 255) / 256, 256, 0, stream>>>(
            rays, gh, out, n_rays);
    } else {
        int total_threads = n_rays * 4;
        transmittance_kernel<<<(total_threads + 255) / 256, 256, 0, stream>>>(
            rays, grid, out, n_rays);
    }
}

// Round 3
// 161.749 us; speedup vs baseline: 1.2061x; 1.2061x over previous
//
#include <hip/hip_runtime.h>
#include <hip/hip_fp16.h>
#include <math.h>
#include <stdint.h>

#define N_STEPS 256
#define DENSITY_SCALE 10.0f
#define REF_EPS 1e-8f

typedef uint32_t u32_a2 __attribute__((aligned(2)));
typedef uint2 uint2_a4 __attribute__((aligned(4)));

__device__ __forceinline__ float clip01(float v) {
    return fminf(fmaxf(v, 0.0f), 1.0f);
}

__device__ __forceinline__ float safe_inv(float d) {
    float denom = d;
    if (fabsf(d) < REF_EPS) {
        float s = (d > 0.0f) ? 1.0f : ((d < 0.0f) ? -1.0f : 0.0f);
        denom = s * REF_EPS + REF_EPS;   // may be 0 -> inf, matches jnp
    }
    return 1.0f / denom;
}

__device__ __forceinline__ uint32_t q255(float v) {
    return (uint32_t)__float2int_rn(clip01(v) * 255.0f);
}

// ---- repack: quad[z][y][x] = u8x4 {v(z,y,x), v(z,y+1,x), v(z+1,y,x), v(z+1,y+1,x)} ----
// One thread per 4 consecutive x. One-pass (L3 absorbs the 4x row re-reads; the
// two-pass variant regressed: +16MB workspace costs more in harness re-poison
// than the saved read traffic).
__global__ __launch_bounds__(256) void repack_quad_kernel(
    const float* __restrict__ g, uint32_t* __restrict__ quad)
{
    int t = blockIdx.x * blockDim.x + threadIdx.x;     // [0, 256*256*64)
    int x4 = (t & 63) << 2;
    int zy = t >> 6;
    int z = zy >> 8;
    int y = zy & 255;
    int yp = (y == 255) ? y : y + 1;                   // clamped rows: values unused by march
    int zp = (z == 255) ? z : z + 1;
    float4 a = *(const float4*)(g + ((z  << 16) + (y  << 8) + x4));   // (z,  y )
    float4 b = *(const float4*)(g + ((z  << 16) + (yp << 8) + x4));   // (z,  y+1)
    float4 c = *(const float4*)(g + ((zp << 16) + (y  << 8) + x4));   // (z+1,y )
    float4 d = *(const float4*)(g + ((zp << 16) + (yp << 8) + x4));   // (z+1,y+1)
    uint4 o;
    o.x = q255(a.x) | (q255(b.x) << 8) | (q255(c.x) << 16) | (q255(d.x) << 24);
    o.y = q255(a.y) | (q255(b.y) << 8) | (q255(c.y) << 16) | (q255(d.y) << 24);
    o.z = q255(a.z) | (q255(b.z) << 8) | (q255(c.z) << 16) | (q255(d.z) << 24);
    o.w = q255(a.w) | (q255(b.w) << 8) | (q255(c.w) << 16) | (q255(d.w) << 24);
    *(uint4*)(quad + ((zy << 8) + x4)) = o;
}

// -------- march: 16 threads/ray over ALL rays, inline slab test, u8 quad grid --------
// No compaction pass: the slab test (~30 VALU) is free next to a 256-sample
// fetch-bound march, validity is uniform within each 16-lane group (same ray),
// and R0/R1 proved 28% marching occupancy already saturates the fetch wall —
// so the ~53% invalid-ray waves retiring early cost nothing. Removing setup
// saves a dispatch plus 2.3 MB of workspace (re-poison time scales with ws).
__global__ __launch_bounds__(256, 8) void march_all_kernel(
    const float* __restrict__ rays, const uint32_t* __restrict__ quad,
    float* __restrict__ out, int n_rays)
{
    int gid = blockIdx.x * blockDim.x + threadIdx.x;
    int sub = gid & 15;
    int stride = (gridDim.x * blockDim.x) >> 4;

    for (int ray = gid >> 4; ray < n_rays; ray += stride) {
        const float* r = rays + ray * 6;           // 16 lanes same addr -> L1 broadcast
        float ox = r[0], oy = r[1], oz = r[2];
        float dx = r[3], dy = r[4], dz = r[5];
        float nrm = sqrtf(dx*dx + dy*dy + dz*dz) + REF_EPS;
        float inv_n = 1.0f / nrm;
        dx *= inv_n; dy *= inv_n; dz *= inv_n;
        float ixv = safe_inv(dx), iyv = safe_inv(dy), izv = safe_inv(dz);
        float tax = (-1.0f - ox) * ixv, tbx = (1.0f - ox) * ixv;
        float tay = (-1.0f - oy) * iyv, tby = (1.0f - oy) * iyv;
        float taz = (-1.0f - oz) * izv, tbz = (1.0f - oz) * izv;
        float tmin = fmaxf(fmaxf(fminf(tax, tbx), fminf(tay, tby)), fminf(taz, tbz));
        float tmax = fminf(fminf(fmaxf(tax, tbx), fmaxf(tay, tby)), fmaxf(taz, tbz));
        tmin = fmaxf(tmin, 0.0f);
        if (!(tmax > tmin)) {
            if (sub == 0) out[ray] = 1.0f;
            continue;
        }
        float seg = tmax - tmin;

        // gx(i) = (ox + (tmin + seg*(i+0.5)/256)*dx + 1) * 127.5  ==  gx0 + i*gsx
        float s   = seg * (1.0f / (float)N_STEPS);
        float t0  = fmaf(0.5f, s, tmin);
        float dxs = dx * 127.5f, dys = dy * 127.5f, dzs = dz * 127.5f;
        float gsx = dxs * s, gsy = dys * s, gsz = dzs * s;
        float gx0 = fmaf(t0, dxs, fmaf(ox, 127.5f, 127.5f));
        float gy0 = fmaf(t0, dys, fmaf(oy, 127.5f, 127.5f));
        float gz0 = fmaf(t0, dzs, fmaf(oz, 127.5f, 127.5f));

        float sum = 0.0f;
        #pragma unroll 8
        for (int i = sub; i < N_STEPS; i += 16) {
            float fi = (float)i;
            float gx = fmaf(fi, gsx, gx0);
            float gy = fmaf(fi, gsy, gy0);
            float gz = fmaf(fi, gsz, gz0);

            float fx0 = floorf(gx), fy0 = floorf(gy), fz0 = floorf(gz);
            int x0 = (int)fminf(fmaxf(fx0, 0.0f), 254.0f);
            int y0 = (int)fminf(fmaxf(fy0, 0.0f), 254.0f);
            int z0 = (int)fminf(fmaxf(fz0, 0.0f), 254.0f);
            float fx = fminf(fmaxf(gx - (float)x0, 0.0f), 1.0f);
            float fy = fminf(fmaxf(gy - (float)y0, 0.0f), 1.0f);
            float fz = fminf(fmaxf(gz - (float)z0, 0.0f), 1.0f);

            int vidx = (z0 << 16) + (y0 << 8) + x0;
            uint2 v = *(const uint2_a4*)(quad + vidx);
            // v.x bytes: c000,c010,c100,c110 ; v.y bytes: c001,c011,c101,c111
            float c000 = (float)( v.x        & 0xffu);
            float c010 = (float)((v.x >>  8) & 0xffu);
            float c100 = (float)((v.x >> 16) & 0xffu);
            float c110 = (float)( v.x >> 24        );
            float c001 = (float)( v.y        & 0xffu);
            float c011 = (float)((v.y >>  8) & 0xffu);
            float c101 = (float)((v.y >> 16) & 0xffu);
            float c111 = (float)( v.y >> 24        );

            float omfx = 1.0f - fx;
            float c00 = c000 * omfx + c001 * fx;
            float c01 = c010 * omfx + c011 * fx;
            float c10 = c100 * omfx + c101 * fx;
            float c11 = c110 * omfx + c111 * fx;
            float omfy = 1.0f - fy;
            float cc0 = c00 * omfy + c01 * fy;
            float cc1 = c10 * omfy + c11 * fy;
            sum += cc0 * (1.0f - fz) + cc1 * fz;   // scaled by 255
        }

        sum += __shfl_xor(sum, 1);
        sum += __shfl_xor(sum, 2);
        sum += __shfl_xor(sum, 4);
        sum += __shfl_xor(sum, 8);

        if (sub == 0) {
            float dt = seg * (1.0f / (float)N_STEPS);
            float tau = (DENSITY_SCALE / 255.0f) * sum * dt;
            out[ray] = expf(-tau);
        }
    }
}

// ---------------- fallback: fp16 flat grid, 8 threads per ray ----------------
__global__ __launch_bounds__(256) void repack_kernel(
    const float* __restrict__ g, __half* __restrict__ gh, int n)
{
    int i = (blockIdx.x * blockDim.x + threadIdx.x) * 4;
    if (i >= n) return;
    float4 v = *(const float4*)(g + i);
    __half2* dst = (__half2*)(gh + i);
    dst[0] = __floats2half2_rn(clip01(v.x), clip01(v.y));
    dst[1] = __floats2half2_rn(clip01(v.z), clip01(v.w));
}

__global__ __launch_bounds__(256) void transmittance_h_kernel(
    const float* __restrict__ rays, const __half* __restrict__ gh,
    float* __restrict__ out, int n_rays)
{
    int gid = blockIdx.x * blockDim.x + threadIdx.x;
    int ray = gid >> 3;
    int sub = gid & 7;
    if (ray >= n_rays) return;

    const float* r = rays + ray * 6;
    float ox = r[0], oy = r[1], oz = r[2];
    float dx = r[3], dy = r[4], dz = r[5];
    float nrm = sqrtf(dx*dx + dy*dy + dz*dz) + REF_EPS;
    float inv_n = 1.0f / nrm;
    dx *= inv_n; dy *= inv_n; dz *= inv_n;
    float ixv = safe_inv(dx), iyv = safe_inv(dy), izv = safe_inv(dz);
    float tax = (-1.0f - ox) * ixv, tbx = (1.0f - ox) * ixv;
    float tay = (-1.0f - oy) * iyv, tby = (1.0f - oy) * iyv;
    float taz = (-1.0f - oz) * izv, tbz = (1.0f - oz) * izv;
    float tmin = fmaxf(fmaxf(fminf(tax, tbx), fminf(tay, tby)), fminf(taz, tbz));
    float tmax = fminf(fminf(fmaxf(tax, tbx), fmaxf(tay, tby)), fmaxf(taz, tbz));
    tmin = fmaxf(tmin, 0.0f);
    bool valid = tmax > tmin;
    float seg = valid ? (tmax - tmin) : 0.0f;
    float sum = 0.0f;

    if (valid) {
        #pragma unroll 4
        for (int i = sub; i < N_STEPS; i += 8) {
            float frac = ((float)i + 0.5f) * (1.0f / (float)N_STEPS);
            float t = fmaf(seg, frac, tmin);
            float px = fmaf(t, dx, ox);
            float py = fmaf(t, dy, oy);
            float pz = fmaf(t, dz, oz);
            float gx = (px + 1.0f) * (0.5f * 255.0f);
            float gy = (py + 1.0f) * (0.5f * 255.0f);
            float gz = (pz + 1.0f) * (0.5f * 255.0f);
            float fx0 = floorf(gx), fy0 = floorf(gy), fz0 = floorf(gz);
            int x0 = (int)fminf(fmaxf(fx0, 0.0f), 254.0f);
            int y0 = (int)fminf(fmaxf(fy0, 0.0f), 254.0f);
            int z0 = (int)fminf(fmaxf(fz0, 0.0f), 254.0f);
            float fx = fminf(fmaxf(gx - (float)x0, 0.0f), 1.0f);
            float fy = fminf(fmaxf(gy - (float)y0, 0.0f), 1.0f);
            float fz = fminf(fmaxf(gz - (float)z0, 0.0f), 1.0f);
            const __half* p0 = gh + ((z0 << 16) + (y0 << 8) + x0);
            u32_a2 a00 = *(const u32_a2*)(const void*)(p0);
            u32_a2 a01 = *(const u32_a2*)(const void*)(p0 + 256);
            u32_a2 a10 = *(const u32_a2*)(const void*)(p0 + 65536);
            u32_a2 a11 = *(const u32_a2*)(const void*)(p0 + 65536 + 256);
            float2 f00 = __half22float2(*(__half2*)&a00);
            float2 f01 = __half22float2(*(__half2*)&a01);
            float2 f10 = __half22float2(*(__half2*)&a10);
            float2 f11 = __half22float2(*(__half2*)&a11);
            float omfx = 1.0f - fx;
            float c00 = f00.x * omfx + f00.y * fx;
            float c01 = f01.x * omfx + f01.y * fx;
            float c10 = f10.x * omfx + f10.y * fx;
            float c11 = f11.x * omfx + f11.y * fx;
            float omfy = 1.0f - fy;
            float cc0 = c00 * omfy + c01 * fy;
            float cc1 = c10 * omfy + c11 * fy;
            sum += cc0 * (1.0f - fz) + cc1 * fz;
        }
    }

    sum += __shfl_xor(sum, 1);
    sum += __shfl_xor(sum, 2);
    sum += __shfl_xor(sum, 4);

    if (sub == 0) {
        float result = 1.0f;
        if (valid) {
            float dt = seg * (1.0f / (float)N_STEPS);
            float tau = DENSITY_SCALE * sum * dt;
            result = expf(-tau);
        }
        out[ray] = result;
    }
}

// ---------------- fallback: fp32 grid, 4 threads per ray ----------
__global__ __launch_bounds__(256) void transmittance_kernel(
    const float* __restrict__ rays, const float* __restrict__ grid,
    float* __restrict__ out, int n_rays)
{
    int gid = blockIdx.x * blockDim.x + threadIdx.x;
    int ray = gid >> 2;
    int sub = gid & 3;
    if (ray >= n_rays) return;
    const float* r = rays + ray * 6;
    float ox = r[0], oy = r[1], oz = r[2];
    float dx = r[3], dy = r[4], dz = r[5];
    float nrm = sqrtf(dx*dx + dy*dy + dz*dz) + REF_EPS;
    float inv_n = 1.0f / nrm;
    dx *= inv_n; dy *= inv_n; dz *= inv_n;
    float ixv = safe_inv(dx), iyv = safe_inv(dy), izv = safe_inv(dz);
    float tax = (-1.0f - ox) * ixv, tbx = (1.0f - ox) * ixv;
    float tay = (-1.0f - oy) * iyv, tby = (1.0f - oy) * iyv;
    float taz = (-1.0f - oz) * izv, tbz = (1.0f - oz) * izv;
    float tmin = fmaxf(fmaxf(fminf(tax, tbx), fminf(tay, tby)), fminf(taz, tbz));
    float tmax = fminf(fminf(fmaxf(tax, tbx), fmaxf(tay, tby)), fmaxf(taz, tbz));
    tmin = fmaxf(tmin, 0.0f);
    bool valid = tmax > tmin;
    float result = 1.0f;
    float seg = valid ? (tmax - tmin) : 0.0f;
    float sum = 0.0f;
    if (valid) {
        #pragma unroll 4
        for (int i = sub; i < N_STEPS; i += 4) {
            float frac = ((float)i + 0.5f) * (1.0f / (float)N_STEPS);
            float t = fmaf(seg, frac, tmin);
            float px = fmaf(t, dx, ox);
            float py = fmaf(t, dy, oy);
            float pz = fmaf(t, dz, oz);
            float gx = (px + 1.0f) * (0.5f * 255.0f);
            float gy = (py + 1.0f) * (0.5f * 255.0f);
            float gz = (pz + 1.0f) * (0.5f * 255.0f);
            float fx0 = floorf(gx), fy0 = floorf(gy), fz0 = floorf(gz);
            int x0 = (int)fminf(fmaxf(fx0, 0.0f), 254.0f);
            int y0 = (int)fminf(fmaxf(fy0, 0.0f), 254.0f);
            int z0 = (int)fminf(fmaxf(fz0, 0.0f), 254.0f);
            float fx = fminf(fmaxf(gx - (float)x0, 0.0f), 1.0f);
            float fy = fminf(fmaxf(gy - (float)y0, 0.0f), 1.0f);
            float fz = fminf(fmaxf(gz - (float)z0, 0.0f), 1.0f);
            const float* p0 = grid + ((z0 << 16) + (y0 << 8) + x0);
            const float* p1 = p0 + 65536;
            float c000 = p0[0],   c001 = p0[1];
            float c010 = p0[256], c011 = p0[257];
            float c100 = p1[0],   c101 = p1[1];
            float c110 = p1[256], c111 = p1[257];
            float omfx = 1.0f - fx;
            float c00 = c000 * omfx + c001 * fx;
            float c01 = c010 * omfx + c011 * fx;
            float c10 = c100 * omfx + c101 * fx;
            float c11 = c110 * omfx + c111 * fx;
            float omfy = 1.0f - fy;
            float cc0 = c00 * omfy + c01 * fy;
            float cc1 = c10 * omfy + c11 * fy;
            sum += cc0 * (1.0f - fz) + cc1 * fz;
        }
    }
    sum += __shfl_xor(sum, 1);
    sum += __shfl_xor(sum, 2);
    if (valid) {
        float dt = seg * (1.0f / (float)N_STEPS);
        float tau = DENSITY_SCALE * sum * dt;
        result = expf(-tau);
    }
    if (sub == 0) out[ray] = result;
}

extern "C" void kernel_launch(void* const* d_in, const int* in_sizes, int n_in,
                              void* d_out, int out_size, void* d_ws, size_t ws_size,
                              hipStream_t stream) {
    const float* rays = (const float*)d_in[0];   // [65536, 6] fp32
    const float* grid = (const float*)d_in[1];   // [256,256,256] fp32
    float* out = (float*)d_out;
    int n_rays = in_sizes[0] / 6;
    int n_grid = in_sizes[1];                    // 16777216

    const size_t QUAD_BYTES = (size_t)n_grid * 4;          // 64 MB u8-quad grid
    const size_t need_half  = (size_t)n_grid * 2;          // 32 MB fp16 grid

    if (ws_size >= QUAD_BYTES) {
        // minimal-workspace path: quad table only (64 MB), 2 dispatches total
        uint32_t* quad = (uint32_t*)d_ws;
        int rp_threads = n_grid / 4;
        repack_quad_kernel<<<(rp_threads + 255) / 256, 256, 0, stream>>>(grid, quad);
        // 16 threads/ray over all rays: 4096 blocks * 256 / 16 = 65536 ray slots
        march_all_kernel<<<4096, 256, 0, stream>>>(rays, quad, out, n_rays);
    } else if (ws_size >= need_half) {
        __half* gh = (__half*)d_ws;
        int rp_threads = n_grid / 4;
        repack_kernel<<<(rp_threads + 255) / 256, 256, 0, stream>>>(grid, gh, n_grid);
        int total_threads = n_rays * 8;
        transmittance_h_kernel<<<(total_threads + 255) / 256, 256, 0, stream>>>(
            rays, gh, out, n_rays);
    } else {
        int total_threads = n_rays * 4;
        transmittance_kernel<<<(total_threads + 255) / 256, 256, 0, stream>>>(
            rays, grid, out, n_rays);
    }
}

// Round 4
// 151.048 us; speedup vs baseline: 1.2916x; 1.0708x over previous
//
#include <hip/hip_runtime.h>
#include <hip/hip_fp16.h>
#include <math.h>
#include <stdint.h>

#define N_STEPS 256
#define DENSITY_SCALE 10.0f
#define REF_EPS 1e-8f

typedef uint32_t u32_a2 __attribute__((aligned(2)));

__device__ __forceinline__ float clip01(float v) {
    return fminf(fmaxf(v, 0.0f), 1.0f);
}

__device__ __forceinline__ float safe_inv(float d) {
    float denom = d;
    if (fabsf(d) < REF_EPS) {
        float s = (d > 0.0f) ? 1.0f : ((d < 0.0f) ? -1.0f : 0.0f);
        denom = s * REF_EPS + REF_EPS;   // may be 0 -> inf, matches jnp
    }
    return 1.0f / denom;
}

__device__ __forceinline__ uint32_t q255(float v) {
    return (uint32_t)__float2int_rn(clip01(v) * 255.0f);
}

// ---- brick repack --------------------------------------------------------
// Quad entry for voxel (z,y,x): u8x4 {v(z,y,x), v(z,y+1,x), v(z+1,y,x), v(z+1,y+1,x)}.
// Entries are tiled into 4x2x2-voxel bricks: one brick = 16 entries = exactly one
// 64B cache line. Line footprint per ray drops ~35% vs row-major (line-changes
// were driven by 1-voxel y/z extent; bricks give 2x2 y/z extent per line).
// One thread per brick: reads 9 float4 grid rows (z0..z0+2 x y0..y0+2, clamped),
// writes 64B contiguous.
__global__ __launch_bounds__(256) void repack_brick_kernel(
    const float* __restrict__ g, uint32_t* __restrict__ quad)
{
    int t = blockIdx.x * blockDim.x + threadIdx.x;   // [0, 1<<20) bricks
    int bx = t & 63;
    int byz = t >> 6;
    int by = byz & 127;
    int bz = byz >> 7;
    int x4 = bx << 2;
    int y0 = by << 1;
    int z0 = bz << 1;

    // quantized 4-wide rows: qr[dz][dy][lx], dz,dy in 0..2 (clamped at 255)
    uint32_t qr[3][3][4];
    #pragma unroll
    for (int dz = 0; dz < 3; ++dz) {
        int z = z0 + dz; if (z > 255) z = 255;
        #pragma unroll
        for (int dy = 0; dy < 3; ++dy) {
            int y = y0 + dy; if (y > 255) y = 255;
            float4 r = *(const float4*)(g + ((z << 16) + (y << 8) + x4));
            qr[dz][dy][0] = q255(r.x);
            qr[dz][dy][1] = q255(r.y);
            qr[dz][dy][2] = q255(r.z);
            qr[dz][dy][3] = q255(r.w);
        }
    }

    uint32_t* dst = quad + ((size_t)t << 4);
    #pragma unroll
    for (int lz = 0; lz < 2; ++lz) {
        #pragma unroll
        for (int ly = 0; ly < 2; ++ly) {
            uint4 o;
            uint32_t* po = (uint32_t*)&o;
            #pragma unroll
            for (int lx = 0; lx < 4; ++lx) {
                po[lx] = qr[lz][ly][lx]
                       | (qr[lz][ly + 1][lx] << 8)
                       | (qr[lz + 1][ly][lx] << 16)
                       | (qr[lz + 1][ly + 1][lx] << 24);
            }
            // entry offset within brick: lx + (ly<<2) + (lz<<3); lx-run is contiguous
            *(uint4*)(dst + ((ly << 2) + (lz << 3))) = o;
        }
    }
}

// -------- march: 16 threads/ray over ALL rays, inline slab test, bricked quad ----
__global__ __launch_bounds__(256, 8) void march_all_kernel(
    const float* __restrict__ rays, const uint32_t* __restrict__ quad,
    float* __restrict__ out, int n_rays)
{
    int gid = blockIdx.x * blockDim.x + threadIdx.x;
    int sub = gid & 15;
    int stride = (gridDim.x * blockDim.x) >> 4;

    for (int ray = gid >> 4; ray < n_rays; ray += stride) {
        const float* r = rays + ray * 6;           // 16 lanes same addr -> broadcast
        float ox = r[0], oy = r[1], oz = r[2];
        float dx = r[3], dy = r[4], dz = r[5];
        float nrm = sqrtf(dx*dx + dy*dy + dz*dz) + REF_EPS;
        float inv_n = 1.0f / nrm;
        dx *= inv_n; dy *= inv_n; dz *= inv_n;
        float ixv = safe_inv(dx), iyv = safe_inv(dy), izv = safe_inv(dz);
        float tax = (-1.0f - ox) * ixv, tbx = (1.0f - ox) * ixv;
        float tay = (-1.0f - oy) * iyv, tby = (1.0f - oy) * iyv;
        float taz = (-1.0f - oz) * izv, tbz = (1.0f - oz) * izv;
        float tmin = fmaxf(fmaxf(fminf(tax, tbx), fminf(tay, tby)), fminf(taz, tbz));
        float tmax = fminf(fminf(fmaxf(tax, tbx), fmaxf(tay, tby)), fmaxf(taz, tbz));
        tmin = fmaxf(tmin, 0.0f);
        if (!(tmax > tmin)) {
            if (sub == 0) out[ray] = 1.0f;
            continue;
        }
        float seg = tmax - tmin;

        // gx(i) = (ox + (tmin + seg*(i+0.5)/256)*dx + 1) * 127.5  ==  gx0 + i*gsx
        float s   = seg * (1.0f / (float)N_STEPS);
        float t0  = fmaf(0.5f, s, tmin);
        float dxs = dx * 127.5f, dys = dy * 127.5f, dzs = dz * 127.5f;
        float gsx = dxs * s, gsy = dys * s, gsz = dzs * s;
        float gx0 = fmaf(t0, dxs, fmaf(ox, 127.5f, 127.5f));
        float gy0 = fmaf(t0, dys, fmaf(oy, 127.5f, 127.5f));
        float gz0 = fmaf(t0, dzs, fmaf(oz, 127.5f, 127.5f));

        float sum = 0.0f;
        #pragma unroll 8
        for (int i = sub; i < N_STEPS; i += 16) {
            float fi = (float)i;
            float gx = fmaf(fi, gsx, gx0);
            float gy = fmaf(fi, gsy, gy0);
            float gz = fmaf(fi, gsz, gz0);

            float fx0 = floorf(gx), fy0 = floorf(gy), fz0 = floorf(gz);
            int x0 = (int)fminf(fmaxf(fx0, 0.0f), 254.0f);
            int y0 = (int)fminf(fmaxf(fy0, 0.0f), 254.0f);
            int z0 = (int)fminf(fmaxf(fz0, 0.0f), 254.0f);
            float fx = fminf(fmaxf(gx - (float)x0, 0.0f), 1.0f);
            float fy = fminf(fmaxf(gy - (float)y0, 0.0f), 1.0f);
            float fz = fminf(fmaxf(gz - (float)z0, 0.0f), 1.0f);

            // brick address: brick(bx,by,bz) = (bz<<13)+(by<<6)+bx; entry = brick*16 +
            // (x&3) + ((y&1)<<2) + ((z&1)<<3). x0+1 may straddle into next brick.
            int base = ((((z0 >> 1) << 13) + ((y0 >> 1) << 6)) << 4)
                     + ((y0 & 1) << 2) + ((z0 & 1) << 3);
            int x1 = x0 + 1;
            int a0 = base + ((x0 >> 2) << 4) + (x0 & 3);
            int a1 = base + ((x1 >> 2) << 4) + (x1 & 3);
            uint32_t w0 = quad[a0];
            uint32_t w1 = quad[a1];
            // w0 bytes: c000,c010,c100,c110 (at x0); w1: c001,c011,c101,c111 (at x0+1)
            float c000 = (float)( w0        & 0xffu);
            float c010 = (float)((w0 >>  8) & 0xffu);
            float c100 = (float)((w0 >> 16) & 0xffu);
            float c110 = (float)( w0 >> 24        );
            float c001 = (float)( w1        & 0xffu);
            float c011 = (float)((w1 >>  8) & 0xffu);
            float c101 = (float)((w1 >> 16) & 0xffu);
            float c111 = (float)( w1 >> 24        );

            float omfx = 1.0f - fx;
            float c00 = c000 * omfx + c001 * fx;
            float c01 = c010 * omfx + c011 * fx;
            float c10 = c100 * omfx + c101 * fx;
            float c11 = c110 * omfx + c111 * fx;
            float omfy = 1.0f - fy;
            float cc0 = c00 * omfy + c01 * fy;
            float cc1 = c10 * omfy + c11 * fy;
            sum += cc0 * (1.0f - fz) + cc1 * fz;   // scaled by 255
        }

        sum += __shfl_xor(sum, 1);
        sum += __shfl_xor(sum, 2);
        sum += __shfl_xor(sum, 4);
        sum += __shfl_xor(sum, 8);

        if (sub == 0) {
            float dt = seg * (1.0f / (float)N_STEPS);
            float tau = (DENSITY_SCALE / 255.0f) * sum * dt;
            out[ray] = expf(-tau);
        }
    }
}

// ---------------- fallback: fp16 flat grid, 8 threads per ray ----------------
__global__ __launch_bounds__(256) void repack_kernel(
    const float* __restrict__ g, __half* __restrict__ gh, int n)
{
    int i = (blockIdx.x * blockDim.x + threadIdx.x) * 4;
    if (i >= n) return;
    float4 v = *(const float4*)(g + i);
    __half2* dst = (__half2*)(gh + i);
    dst[0] = __floats2half2_rn(clip01(v.x), clip01(v.y));
    dst[1] = __floats2half2_rn(clip01(v.z), clip01(v.w));
}

__global__ __launch_bounds__(256) void transmittance_h_kernel(
    const float* __restrict__ rays, const __half* __restrict__ gh,
    float* __restrict__ out, int n_rays)
{
    int gid = blockIdx.x * blockDim.x + threadIdx.x;
    int ray = gid >> 3;
    int sub = gid & 7;
    if (ray >= n_rays) return;

    const float* r = rays + ray * 6;
    float ox = r[0], oy = r[1], oz = r[2];
    float dx = r[3], dy = r[4], dz = r[5];
    float nrm = sqrtf(dx*dx + dy*dy + dz*dz) + REF_EPS;
    float inv_n = 1.0f / nrm;
    dx *= inv_n; dy *= inv_n; dz *= inv_n;
    float ixv = safe_inv(dx), iyv = safe_inv(dy), izv = safe_inv(dz);
    float tax = (-1.0f - ox) * ixv, tbx = (1.0f - ox) * ixv;
    float tay = (-1.0f - oy) * iyv, tby = (1.0f - oy) * iyv;
    float taz = (-1.0f - oz) * izv, tbz = (1.0f - oz) * izv;
    float tmin = fmaxf(fmaxf(fminf(tax, tbx), fminf(tay, tby)), fminf(taz, tbz));
    float tmax = fminf(fminf(fmaxf(tax, tbx), fmaxf(tay, tby)), fmaxf(taz, tbz));
    tmin = fmaxf(tmin, 0.0f);
    bool valid = tmax > tmin;
    float seg = valid ? (tmax - tmin) : 0.0f;
    float sum = 0.0f;

    if (valid) {
        #pragma unroll 4
        for (int i = sub; i < N_STEPS; i += 8) {
            float frac = ((float)i + 0.5f) * (1.0f / (float)N_STEPS);
            float t = fmaf(seg, frac, tmin);
            float px = fmaf(t, dx, ox);
            float py = fmaf(t, dy, oy);
            float pz = fmaf(t, dz, oz);
            float gx = (px + 1.0f) * (0.5f * 255.0f);
            float gy = (py + 1.0f) * (0.5f * 255.0f);
            float gz = (pz + 1.0f) * (0.5f * 255.0f);
            float fx0 = floorf(gx), fy0 = floorf(gy), fz0 = floorf(gz);
            int x0 = (int)fminf(fmaxf(fx0, 0.0f), 254.0f);
            int y0 = (int)fminf(fmaxf(fy0, 0.0f), 254.0f);
            int z0 = (int)fminf(fmaxf(fz0, 0.0f), 254.0f);
            float fx = fminf(fmaxf(gx - (float)x0, 0.0f), 1.0f);
            float fy = fminf(fmaxf(gy - (float)y0, 0.0f), 1.0f);
            float fz = fminf(fmaxf(gz - (float)z0, 0.0f), 1.0f);
            const __half* p0 = gh + ((z0 << 16) + (y0 << 8) + x0);
            u32_a2 a00 = *(const u32_a2*)(const void*)(p0);
            u32_a2 a01 = *(const u32_a2*)(const void*)(p0 + 256);
            u32_a2 a10 = *(const u32_a2*)(const void*)(p0 + 65536);
            u32_a2 a11 = *(const u32_a2*)(const void*)(p0 + 65536 + 256);
            float2 f00 = __half22float2(*(__half2*)&a00);
            float2 f01 = __half22float2(*(__half2*)&a01);
            float2 f10 = __half22float2(*(__half2*)&a10);
            float2 f11 = __half22float2(*(__half2*)&a11);
            float omfx = 1.0f - fx;
            float c00 = f00.x * omfx + f00.y * fx;
            float c01 = f01.x * omfx + f01.y * fx;
            float c10 = f10.x * omfx + f10.y * fx;
            float c11 = f11.x * omfx + f11.y * fx;
            float omfy = 1.0f - fy;
            float cc0 = c00 * omfy + c01 * fy;
            float cc1 = c10 * omfy + c11 * fy;
            sum += cc0 * (1.0f - fz) + cc1 * fz;
        }
    }

    sum += __shfl_xor(sum, 1);
    sum += __shfl_xor(sum, 2);
    sum += __shfl_xor(sum, 4);

    if (sub == 0) {
        float result = 1.0f;
        if (valid) {
            float dt = seg * (1.0f / (float)N_STEPS);
            float tau = DENSITY_SCALE * sum * dt;
            result = expf(-tau);
        }
        out[ray] = result;
    }
}

// ---------------- fallback: fp32 grid, 4 threads per ray ----------
__global__ __launch_bounds__(256) void transmittance_kernel(
    const float* __restrict__ rays, const float* __restrict__ grid,
    float* __restrict__ out, int n_rays)
{
    int gid = blockIdx.x * blockDim.x + threadIdx.x;
    int ray = gid >> 2;
    int sub = gid & 3;
    if (ray >= n_rays) return;
    const float* r = rays + ray * 6;
    float ox = r[0], oy = r[1], oz = r[2];
    float dx = r[3], dy = r[4], dz = r[5];
    float nrm = sqrtf(dx*dx + dy*dy + dz*dz) + REF_EPS;
    float inv_n = 1.0f / nrm;
    dx *= inv_n; dy *= inv_n; dz *= inv_n;
    float ixv = safe_inv(dx), iyv = safe_inv(dy), izv = safe_inv(dz);
    float tax = (-1.0f - ox) * ixv, tbx = (1.0f - ox) * ixv;
    float tay = (-1.0f - oy) * iyv, tby = (1.0f - oy) * iyv;
    float taz = (-1.0f - oz) * izv, tbz = (1.0f - oz) * izv;
    float tmin = fmaxf(fmaxf(fminf(tax, tbx), fminf(tay, tby)), fminf(taz, tbz));
    float tmax = fminf(fminf(fmaxf(tax, tbx), fmaxf(tay, tby)), fmaxf(taz, tbz));
    tmin = fmaxf(tmin, 0.0f);
    bool valid = tmax > tmin;
    float result = 1.0f;
    float seg = valid ? (tmax - tmin) : 0.0f;
    float sum = 0.0f;
    if (valid) {
        #pragma unroll 4
        for (int i = sub; i < N_STEPS; i += 4) {
            float frac = ((float)i + 0.5f) * (1.0f / (float)N_STEPS);
            float t = fmaf(seg, frac, tmin);
            float px = fmaf(t, dx, ox);
            float py = fmaf(t, dy, oy);
            float pz = fmaf(t, dz, oz);
            float gx = (px + 1.0f) * (0.5f * 255.0f);
            float gy = (py + 1.0f) * (0.5f * 255.0f);
            float gz = (pz + 1.0f) * (0.5f * 255.0f);
            float fx0 = floorf(gx), fy0 = floorf(gy), fz0 = floorf(gz);
            int x0 = (int)fminf(fmaxf(fx0, 0.0f), 254.0f);
            int y0 = (int)fminf(fmaxf(fy0, 0.0f), 254.0f);
            int z0 = (int)fminf(fmaxf(fz0, 0.0f), 254.0f);
            float fx = fminf(fmaxf(gx - (float)x0, 0.0f), 1.0f);
            float fy = fminf(fmaxf(gy - (float)y0, 0.0f), 1.0f);
            float fz = fminf(fmaxf(gz - (float)z0, 0.0f), 1.0f);
            const float* p0 = grid + ((z0 << 16) + (y0 << 8) + x0);
            const float* p1 = p0 + 65536;
            float c000 = p0[0],   c001 = p0[1];
            float c010 = p0[256], c011 = p0[257];
            float c100 = p1[0],   c101 = p1[1];
            float c110 = p1[256], c111 = p1[257];
            float omfx = 1.0f - fx;
            float c00 = c000 * omfx + c001 * fx;
            float c01 = c010 * omfx + c011 * fx;
            float c10 = c100 * omfx + c101 * fx;
            float c11 = c110 * omfx + c111 * fx;
            float omfy = 1.0f - fy;
            float cc0 = c00 * omfy + c01 * fy;
            float cc1 = c10 * omfy + c11 * fy;
            sum += cc0 * (1.0f - fz) + cc1 * fz;
        }
    }
    sum += __shfl_xor(sum, 1);
    sum += __shfl_xor(sum, 2);
    if (valid) {
        float dt = seg * (1.0f / (float)N_STEPS);
        float tau = DENSITY_SCALE * sum * dt;
        result = expf(-tau);
    }
    if (sub == 0) out[ray] = result;
}

extern "C" void kernel_launch(void* const* d_in, const int* in_sizes, int n_in,
                              void* d_out, int out_size, void* d_ws, size_t ws_size,
                              hipStream_t stream) {
    const float* rays = (const float*)d_in[0];   // [65536, 6] fp32
    const float* grid = (const float*)d_in[1];   // [256,256,256] fp32
    float* out = (float*)d_out;
    int n_rays = in_sizes[0] / 6;
    int n_grid = in_sizes[1];                    // 16777216

    const size_t QUAD_BYTES = (size_t)n_grid * 4;          // 64 MB bricked quad grid
    const size_t need_half  = (size_t)n_grid * 2;          // 32 MB fp16 grid

    if (ws_size >= QUAD_BYTES) {
        // minimal-workspace path: bricked quad table only (64 MB), 2 dispatches
        uint32_t* quad = (uint32_t*)d_ws;
        int n_bricks = n_grid / 16;              // 4x2x2 voxels per brick
        repack_brick_kernel<<<n_bricks / 256, 256, 0, stream>>>(grid, quad);
        // 16 threads/ray over all rays: 4096 blocks * 256 / 16 = 65536 ray slots
        march_all_kernel<<<4096, 256, 0, stream>>>(rays, quad, out, n_rays);
    } else if (ws_size >= need_half) {
        __half* gh = (__half*)d_ws;
        int rp_threads = n_grid / 4;
        repack_kernel<<<(rp_threads + 255) / 256, 256, 0, stream>>>(grid, gh, n_grid);
        int total_threads = n_rays * 8;
        transmittance_h_kernel<<<(total_threads + 255) / 256, 256, 0, stream>>>(
            rays, gh, out, n_rays);
    } else {
        int total_threads = n_rays * 4;
        transmittance_kernel<<<(total_threads + 255) / 256, 256, 0, stream>>>(
            rays, grid, out, n_rays);
    }
}